// Round 5
// baseline (1243.693 us; speedup 1.0000x reference)
//
#include <hip/hip_runtime.h>
#include <stdint.h>

#define BATCH    8
#define NITEMS   1000000
#define NC       64           // coarse value bins: floor(s*64)
#define NF       4096         // fine bins within one coarse bin
#define NBLKA    256          // blocks/batch for k_bits
#define NBLKF    128          // blocks/batch for fine/compact (slow path)
#define FASTBLK  16           // blocks/batch for fast fine pass
#define CANDCAP  131072       // per-batch clist capacity
#define CAP      32768        // per-batch cand2 capacity
#define IMG_W    768.0f
#define IMG_H    432.0f

typedef unsigned long long ull;

static __device__ __forceinline__ float clip0(float v, float hi) {
    return fminf(fmaxf(v, 0.0f), hi);
}
static __device__ __forceinline__ int cbin(float s) {
    int g = (int)(s * (float)NC);                   // pow-2 mul: exact, monotone
    return g > NC - 1 ? NC - 1 : (g < 0 ? 0 : g);
}
static __device__ __forceinline__ int fbin(float s, int g) {
    int f = (int)(s * (float)(NC * NF)) - g * NF;   // pow-2 mul: exact, monotone
    return f > NF - 1 ? NF - 1 : (f < 0 ? 0 : f);
}
static __device__ __forceinline__ unsigned mkbits(float4 box, float s) {
    float x1 = clip0(box.x - box.z * 0.5f, IMG_W);
    float x2 = clip0(box.x + box.z * 0.5f, IMG_W);
    float y1 = clip0(box.y - box.w * 0.5f, IMG_H);
    float y2 = clip0(box.y + box.w * 0.5f, IMG_H);
    bool m = ((x2 - x1) > 16.0f) && ((y2 - y1) > 16.0f);
    return __float_as_uint(m ? s : 0.0f);
}

// ---- kernel A: stream bits + coarse hist + top-2-bin candidate append ----
__global__ __launch_bounds__(256)
void k_bits(const float* __restrict__ scores,
            const float4* __restrict__ rps,
            uint4* __restrict__ bits_arr,
            unsigned short* __restrict__ p1,
            ull* __restrict__ clist,
            unsigned* __restrict__ rawCnt) {
    __shared__ unsigned h1[4][NC];
    const int b = blockIdx.y, blk = blockIdx.x, tid = threadIdx.x;
    const int wave = tid >> 6, lane = tid & 63;
    h1[tid >> 6][tid & 63] = 0u;
    __syncthreads();
    const int base = b * NITEMS;
    for (int i0 = (blk * 256 + tid) * 4; i0 < NITEMS; i0 += NBLKA * 256 * 4) {
        const float4 sc = *(const float4*)(scores + base + i0);
        const float4 bx0 = rps[base + i0 + 0];
        const float4 bx1 = rps[base + i0 + 1];
        const float4 bx2 = rps[base + i0 + 2];
        const float4 bx3 = rps[base + i0 + 3];
        unsigned arr[4];
        arr[0] = mkbits(bx0, sc.x);
        arr[1] = mkbits(bx1, sc.y);
        arr[2] = mkbits(bx2, sc.z);
        arr[3] = mkbits(bx3, sc.w);
        bits_arr[(base + i0) >> 2] = make_uint4(arr[0], arr[1], arr[2], arr[3]);
        #pragma unroll
        for (int j = 0; j < 4; j++) {
            bool q = false;
            unsigned bits = arr[j];
            if (bits) {
                int g = cbin(__uint_as_float(bits));
                atomicAdd(&h1[wave][g], 1u);
                q = (g >= NC - 2);
            }
            ull m = __ballot(q);
            if (m) {
                unsigned cnt = (unsigned)__popcll(m);
                unsigned pre = (unsigned)__popcll(m & ((1ULL << lane) - 1ULL));
                int leader = __ffsll((long long)m) - 1;
                unsigned bse = 0;
                if (lane == leader) bse = atomicAdd(&rawCnt[b], cnt);
                bse = (unsigned)__shfl((int)bse, leader);
                if (q) {
                    unsigned slot = bse + pre;
                    if (slot < CANDCAP)
                        clist[(size_t)b * CANDCAP + slot] =
                            ((ull)bits << 32) | (unsigned)(~(unsigned)(i0 + j));
                }
            }
        }
    }
    __syncthreads();
    if (tid < NC) {
        unsigned s = h1[0][tid] + h1[1][tid] + h1[2][tid] + h1[3][tid];
        p1[(size_t)(b * NBLKA + blk) * NC + tid] = (unsigned short)s;
    }
}

// ---- scan1: reduce coarse partials, suffix scan (64 bins), set fast flag ----
__global__ __launch_bounds__(256)
void k_scan1(const unsigned short* __restrict__ p1,
             const unsigned* __restrict__ rawCnt,
             unsigned* __restrict__ chist64,
             unsigned* __restrict__ csuf64,
             unsigned* __restrict__ ctrA,
             unsigned* __restrict__ meta,
             int K) {
    const int b = blockIdx.x, tid = threadIdx.x;
    __shared__ unsigned sm[256];
    const int bin = tid & 63, chunk = tid >> 6;
    unsigned s = 0;
    for (int k = chunk * 64; k < chunk * 64 + 64; ++k)
        s += p1[(size_t)(b * NBLKA + k) * NC + bin];
    sm[tid] = s;
    __syncthreads();
    if (tid < NC) sm[tid] = sm[tid] + sm[64 + tid] + sm[128 + tid] + sm[192 + tid];
    __syncthreads();
    if (tid == 0) {
        unsigned run = 0, cbb = 0, nAb = 0;
        bool found = false;
        for (int g = NC - 1; g >= 0; --g) {
            unsigned c = sm[g];
            chist64[b * NC + g] = c;
            csuf64[b * NC + g] = run;
            if (!found && run < (unsigned)K && run + c >= (unsigned)K) {
                cbb = (unsigned)g; nAb = run; found = true;
            }
            run += c;
        }
        meta[b * 8 + 0] = cbb;
        meta[b * 8 + 1] = nAb;
        unsigned nr = rawCnt[b];
        unsigned fast = (found && cbb >= (unsigned)(NC - 2) && nr <= CANDCAP) ? 1u : 0u;
        meta[b * 8 + 4] = fast;
        meta[b * 8 + 5] = nr > CANDCAP ? CANDCAP : nr;
    }
    if (tid < NC) ctrA[b * NC + tid] = 0u;
}

// ---- fine hist: fast from clist (0.2 MB) or slow from bits_arr (32 MB) ----
__global__ __launch_bounds__(512)
void k_fine(const unsigned* __restrict__ bits_lin,
            const ull* __restrict__ clist,
            const unsigned* __restrict__ meta,
            unsigned short* __restrict__ p2) {
    const int b = blockIdx.y, blk = blockIdx.x, tid = threadIdx.x;
    const unsigned fast = meta[b * 8 + 4];
    const unsigned cbb = meta[b * 8 + 0];
    if (fast && blk >= FASTBLK) return;
    __shared__ unsigned h2[NF];
    for (int k = tid; k < NF; k += 512) h2[k] = 0u;
    __syncthreads();
    if (fast) {
        const unsigned nRaw = meta[b * 8 + 5];
        for (unsigned i = blk * 512 + tid; i < nRaw; i += FASTBLK * 512) {
            unsigned bits = (unsigned)(clist[(size_t)b * CANDCAP + i] >> 32);
            float s = __uint_as_float(bits);
            if ((unsigned)cbin(s) == cbb) atomicAdd(&h2[fbin(s, (int)cbb)], 1u);
        }
    } else {
        const int base = b * NITEMS;
        for (int i = blk * 512 + tid; i < NITEMS; i += NBLKF * 512) {
            unsigned bits = bits_lin[base + i];
            if (!bits) continue;
            float s = __uint_as_float(bits);
            if ((unsigned)cbin(s) == cbb) atomicAdd(&h2[fbin(s, (int)cbb)], 1u);
        }
    }
    __syncthreads();
    const size_t row = (size_t)(b * NBLKF + blk) * NF;
    for (int k = tid; k < NF; k += 512) p2[row + k] = (unsigned short)h2[k];
}

// ---- scan2: reduce fine partials (rowsUsed) + parallel suffix scan ----
__global__ __launch_bounds__(1024)
void k_scan2(const unsigned short* __restrict__ p2,
             unsigned* __restrict__ fhist,
             unsigned* __restrict__ fsuf,
             unsigned* __restrict__ ctrB,
             unsigned* __restrict__ meta,
             int K) {
    const int b = blockIdx.x, tid = threadIdx.x;
    const int rows = meta[b * 8 + 4] ? FASTBLK : NBLKF;
    __shared__ unsigned sc[1024];
    const int binbase = 4 * (1023 - tid);
    unsigned a0 = 0, a1 = 0, a2 = 0, a3 = 0;
    for (int k = 0; k < rows; ++k) {
        const ushort4 v = *(const ushort4*)(p2 + (size_t)(b * NBLKF + k) * NF + binbase);
        a0 += v.x; a1 += v.y; a2 += v.z; a3 += v.w;
    }
    unsigned cw[4] = {a3, a2, a1, a0};
    unsigned pin[4];
    unsigned run = 0;
    #pragma unroll
    for (int k = 0; k < 4; k++) { run += cw[k]; pin[k] = run; }
    sc[tid] = run;
    __syncthreads();
    unsigned x = run;
    for (int off = 1; off < 1024; off <<= 1) {
        unsigned t = (tid >= off) ? sc[tid - off] : 0u;
        __syncthreads();
        x += t;
        sc[tid] = x;
        __syncthreads();
    }
    const unsigned exclBase = x - run;
    const unsigned nAb = meta[b * 8 + 1];
    #pragma unroll
    for (int k = 0; k < 4; k++) {
        int g = binbase + (3 - k);
        unsigned excl = exclBase + pin[k] - cw[k];
        fsuf[b * NF + g] = excl;
        fhist[b * NF + g] = cw[k];
        unsigned t0 = nAb + excl;
        if (t0 < (unsigned)K && t0 + cw[k] >= (unsigned)K) {
            meta[b * 8 + 2] = (unsigned)g;
            meta[b * 8 + 3] = t0 + cw[k];
        }
    }
    if (tid == 0 && nAb + sc[1023] < (unsigned)K) {
        meta[b * 8 + 2] = 0u;
        meta[b * 8 + 3] = nAb + sc[1023];
    }
    ctrB[b * NF + tid * 4 + 0] = 0u;
    ctrB[b * NF + tid * 4 + 1] = 0u;
    ctrB[b * NF + tid * 4 + 2] = 0u;
    ctrB[b * NF + tid * 4 + 3] = 0u;
}

// ---- compact: fast from clist or slow from bits_arr ----
__global__ __launch_bounds__(512)
void k_compact(const uint4* __restrict__ bits_arr,
               const ull* __restrict__ clist,
               const unsigned* __restrict__ meta,
               const unsigned* __restrict__ csuf64,
               const unsigned* __restrict__ fsuf,
               unsigned* __restrict__ ctrA,
               unsigned* __restrict__ ctrB,
               ull* __restrict__ cand) {
    const int b = blockIdx.y;
    const unsigned fast = meta[b * 8 + 4];
    const unsigned cbb = meta[b * 8 + 0];
    const unsigned nAb = meta[b * 8 + 1];
    const unsigned fb  = meta[b * 8 + 2];
    if (fast) {
        const unsigned nRaw = meta[b * 8 + 5];
        for (unsigned i = blockIdx.x * 512 + threadIdx.x; i < nRaw; i += NBLKF * 512) {
            ull key = clist[(size_t)b * CANDCAP + i];
            unsigned bits = (unsigned)(key >> 32);
            float s = __uint_as_float(bits);
            int g = cbin(s);
            if ((unsigned)g < cbb) continue;
            unsigned slot;
            if ((unsigned)g > cbb) {
                slot = csuf64[b * NC + g] + atomicAdd(&ctrA[b * NC + g], 1u);
            } else {
                int f = fbin(s, g);
                if ((unsigned)f < fb) continue;
                slot = nAb + fsuf[b * NF + f] + atomicAdd(&ctrB[b * NF + f], 1u);
            }
            if (slot < CAP) cand[(size_t)b * CAP + slot] = key;
        }
    } else {
        const int base = b * NITEMS;
        for (int i0 = (blockIdx.x * 512 + threadIdx.x) * 4; i0 < NITEMS;
             i0 += NBLKF * 512 * 4) {
            uint4 v = bits_arr[(base + i0) >> 2];
            unsigned arr[4] = {v.x, v.y, v.z, v.w};
            #pragma unroll
            for (int j = 0; j < 4; j++) {
                unsigned bits = arr[j];
                if (!bits) continue;
                float s = __uint_as_float(bits);
                int g = cbin(s);
                if ((unsigned)g < cbb) continue;
                unsigned slot;
                if ((unsigned)g > cbb) {
                    slot = csuf64[b * NC + g] + atomicAdd(&ctrA[b * NC + g], 1u);
                } else {
                    int f = fbin(s, g);
                    if ((unsigned)f < fb) continue;
                    slot = nAb + fsuf[b * NF + f] + atomicAdd(&ctrB[b * NF + f], 1u);
                }
                if (slot < CAP)
                    cand[(size_t)b * CAP + slot] =
                        ((ull)bits << 32) | (unsigned)(~(unsigned)(i0 + j));
            }
        }
    }
}

// ---- rank within tiny segment, gather, write outputs ----
__global__ __launch_bounds__(256)
void k_rank_out(const ull* __restrict__ cand,
                const unsigned* __restrict__ meta,
                const unsigned* __restrict__ csuf64,
                const unsigned* __restrict__ chist64,
                const unsigned* __restrict__ fsuf,
                const unsigned* __restrict__ fhist,
                const float4* __restrict__ rps,
                float* __restrict__ out,
                int K) {
    const int b = blockIdx.y;
    unsigned total = meta[b * 8 + 3];
    if (total > CAP) total = CAP;
    const unsigned p = blockIdx.x * 256 + threadIdx.x;
    if (p >= total) return;
    const ull key = cand[(size_t)b * CAP + p];
    const unsigned bits = (unsigned)(key >> 32);
    const float s = __uint_as_float(bits);
    const unsigned cbb = meta[b * 8 + 0];
    const unsigned nAb = meta[b * 8 + 1];
    int g = cbin(s);
    unsigned sbase, scnt;
    if ((unsigned)g > cbb) {
        sbase = csuf64[b * NC + g];
        scnt  = chist64[b * NC + g];
    } else {
        int f = fbin(s, g);
        sbase = nAb + fsuf[b * NF + f];
        scnt  = fhist[b * NF + f];
    }
    unsigned send = sbase + scnt;
    if (send > total) send = total;
    unsigned rank = sbase;
    for (unsigned j = sbase; j < send; j++)
        rank += (cand[(size_t)b * CAP + j] > key) ? 1u : 0u;
    if (rank < (unsigned)K) {
        unsigned idx = ~((unsigned)key);
        float4 box = rps[(size_t)b * NITEMS + idx];
        float x1 = clip0(box.x - box.z * 0.5f, IMG_W);
        float x2 = clip0(box.x + box.z * 0.5f, IMG_W);
        float y1 = clip0(box.y - box.w * 0.5f, IMG_H);
        float y2 = clip0(box.y + box.w * 0.5f, IMG_H);
        float nw = x2 - x1, nh = y2 - y1;
        float nx = x1 + nw * 0.5f, ny = y1 + nh * 0.5f;
        ((float4*)out)[(size_t)b * K + rank] = make_float4(nx, ny, nw, nh);
        out[(size_t)BATCH * K * 4 + (size_t)b * K + rank] = s;
    }
}

extern "C" void kernel_launch(void* const* d_in, const int* in_sizes, int n_in,
                              void* d_out, int out_size, void* d_ws, size_t ws_size,
                              hipStream_t stream) {
    const float*  scores = (const float*)d_in[0];
    const float4* rps    = (const float4*)d_in[1];
    const int K = out_size / (BATCH * 5);               // 12000

    uint8_t* w = (uint8_t*)d_ws;
    uint4* bits_arr     = (uint4*)(w);                          // 32,000,000 B
    unsigned short* p1  = (unsigned short*)(w + 32000000);      // 262,144 B
    unsigned short* p2  = (unsigned short*)(w + 32300000);      // 8,388,608 B
    unsigned* chist64   = (unsigned*)(w + 40700000);            // 2 KiB
    unsigned* csuf64    = (unsigned*)(w + 40710000);            // 2 KiB
    unsigned* fhist     = (unsigned*)(w + 40800000);            // 128 KiB
    unsigned* fsuf      = (unsigned*)(w + 41000000);            // 128 KiB
    unsigned* ctrA      = (unsigned*)(w + 41200000);            // 2 KiB
    unsigned* ctrB      = (unsigned*)(w + 41210000);            // 128 KiB
    unsigned* meta      = (unsigned*)(w + 41400000);            // 256 B
    unsigned* rawCnt    = (unsigned*)(w + 41410000);            // 32 B
    ull* cand           = (ull*)(w + 41500000);                 // 2 MiB
    ull* clist          = (ull*)(w + 43600000);                 // 8 MiB

    hipMemsetAsync(rawCnt, 0, BATCH * sizeof(unsigned), stream);
    k_bits<<<dim3(NBLKA, BATCH), dim3(256), 0, stream>>>(scores, rps, bits_arr, p1,
                                                         clist, rawCnt);
    k_scan1<<<dim3(BATCH), dim3(256), 0, stream>>>(p1, rawCnt, chist64, csuf64,
                                                   ctrA, meta, K);
    k_fine<<<dim3(NBLKF, BATCH), dim3(512), 0, stream>>>((const unsigned*)bits_arr,
                                                         clist, meta, p2);
    k_scan2<<<dim3(BATCH), dim3(1024), 0, stream>>>(p2, fhist, fsuf, ctrB, meta, K);
    k_compact<<<dim3(NBLKF, BATCH), dim3(512), 0, stream>>>(bits_arr, clist, meta,
                                                            csuf64, fsuf, ctrA, ctrB,
                                                            cand);
    k_rank_out<<<dim3(CAP / 256, BATCH), dim3(256), 0, stream>>>(cand, meta, csuf64,
                                                                 chist64, fsuf, fhist,
                                                                 rps, (float*)d_out, K);
}

// Round 6
// 87.284 us; speedup vs baseline: 14.2489x; 14.2489x over previous
//
#include <hip/hip_runtime.h>
#include <stdint.h>

#define BATCH    8
#define NITEMS   1000000
#define NC       64           // coarse value bins: floor(s*64)
#define NF       4096         // fine bins within one coarse bin
#define NBLKA    256          // blocks/batch for k_bits / fine_fb (p2 rows)
#define NBLKF    128          // blocks/batch for compact
#define CAP      32768        // per-batch cand capacity
#define TOPBIN   (NC - 1)
#define IMG_W    768.0f
#define IMG_H    432.0f

typedef unsigned long long ull;

static __device__ __forceinline__ float clip0(float v, float hi) {
    return fminf(fmaxf(v, 0.0f), hi);
}
static __device__ __forceinline__ int cbin(float s) {
    int g = (int)(s * (float)NC);                   // pow-2 mul: exact, monotone
    return g > NC - 1 ? NC - 1 : (g < 0 ? 0 : g);
}
static __device__ __forceinline__ int fbin(float s, int g) {
    int f = (int)(s * (float)(NC * NF)) - g * NF;   // pow-2 mul: exact, monotone
    return f > NF - 1 ? NF - 1 : (f < 0 ? 0 : f);
}
static __device__ __forceinline__ unsigned mkbits(float4 box, float s) {
    float x1 = clip0(box.x - box.z * 0.5f, IMG_W);
    float x2 = clip0(box.x + box.z * 0.5f, IMG_W);
    float y1 = clip0(box.y - box.w * 0.5f, IMG_H);
    float y2 = clip0(box.y + box.w * 0.5f, IMG_H);
    bool m = ((x2 - x1) > 16.0f) && ((y2 - y1) > 16.0f);
    return __float_as_uint(m ? s : 0.0f);
}

// ---- kernel 1: deep-ILP stream: bits + coarse hist + speculative fine hist ----
// 256 thr/block, (256,4) launch bounds: let the allocator keep 10 vec4 loads
// in flight per thread instead of serializing at 20 VGPRs.
__global__ __launch_bounds__(256, 4)
void k_bits(const float* __restrict__ scores,
            const float4* __restrict__ rps,
            uint4* __restrict__ bits_arr,
            unsigned short* __restrict__ p1,
            unsigned short* __restrict__ p2) {
    __shared__ unsigned h1[4][NC];
    __shared__ unsigned h2[NF];
    const int b = blockIdx.y, blk = blockIdx.x, tid = threadIdx.x;
    const int wave = tid >> 6;
    for (int k = tid; k < NF; k += 256) h2[k] = 0u;
    if (tid < NC) {
        h1[0][tid] = 0u; h1[1][tid] = 0u; h1[2][tid] = 0u; h1[3][tid] = 0u;
    }
    __syncthreads();
    const size_t base = (size_t)b * NITEMS;
    const float4* sp = (const float4*)(scores + base);
    const float4* rp = rps + base;
    for (int i0 = (blk * 256 + tid) * 8; i0 < NITEMS; i0 += NBLKA * 256 * 8) {
        const int q = i0 >> 2;
        // issue all 10 loads as one cluster
        const float4 s0 = sp[q];
        const float4 s1 = sp[q + 1];
        const float4 b0 = rp[i0 + 0];
        const float4 b1 = rp[i0 + 1];
        const float4 b2 = rp[i0 + 2];
        const float4 b3 = rp[i0 + 3];
        const float4 b4 = rp[i0 + 4];
        const float4 b5 = rp[i0 + 5];
        const float4 b6 = rp[i0 + 6];
        const float4 b7 = rp[i0 + 7];
        unsigned arr[8];
        arr[0] = mkbits(b0, s0.x);
        arr[1] = mkbits(b1, s0.y);
        arr[2] = mkbits(b2, s0.z);
        arr[3] = mkbits(b3, s0.w);
        arr[4] = mkbits(b4, s1.x);
        arr[5] = mkbits(b5, s1.y);
        arr[6] = mkbits(b6, s1.z);
        arr[7] = mkbits(b7, s1.w);
        bits_arr[(base >> 2) + q]     = make_uint4(arr[0], arr[1], arr[2], arr[3]);
        bits_arr[(base >> 2) + q + 1] = make_uint4(arr[4], arr[5], arr[6], arr[7]);
        #pragma unroll
        for (int j = 0; j < 8; ++j) {
            unsigned bits = arr[j];
            if (bits) {
                float s = __uint_as_float(bits);
                int g = cbin(s);
                atomicAdd(&h1[wave][g], 1u);
                if (g == TOPBIN) atomicAdd(&h2[fbin(s, TOPBIN)], 1u);
            }
        }
    }
    __syncthreads();
    if (tid < NC)
        p1[(size_t)(b * NBLKA + blk) * NC + tid] =
            (unsigned short)(h1[0][tid] + h1[1][tid] + h1[2][tid] + h1[3][tid]);
    const size_t row2 = (size_t)(b * NBLKA + blk) * NF;
    for (int k = tid; k < NF; k += 256) p2[row2 + k] = (unsigned short)h2[k];
}

// ---- scan1: reduce 256 coarse partial rows + serial suffix scan (64 bins) ----
__global__ __launch_bounds__(256)
void k_scan1(const unsigned short* __restrict__ p1,
             unsigned* __restrict__ chist64,
             unsigned* __restrict__ csuf64,
             unsigned* __restrict__ ctrA,
             unsigned* __restrict__ meta,
             int K) {
    const int b = blockIdx.x, tid = threadIdx.x;
    __shared__ unsigned sm[256];
    const int bin = tid & 63, chunk = tid >> 6;
    unsigned s = 0;
    for (int k = chunk * 64; k < chunk * 64 + 64; ++k)
        s += p1[(size_t)(b * NBLKA + k) * NC + bin];
    sm[tid] = s;
    __syncthreads();
    if (tid < NC) sm[tid] = sm[tid] + sm[64 + tid] + sm[128 + tid] + sm[192 + tid];
    __syncthreads();
    if (tid == 0) {
        unsigned run = 0, cbb = 0, nAb = 0;
        bool found = false;
        for (int g = NC - 1; g >= 0; --g) {
            unsigned c = sm[g];
            chist64[b * NC + g] = c;
            csuf64[b * NC + g] = run;
            if (!found && run < (unsigned)K && run + c >= (unsigned)K) {
                cbb = (unsigned)g; nAb = run; found = true;
            }
            run += c;
        }
        meta[b * 4 + 0] = cbb;
        meta[b * 4 + 1] = nAb;
    }
    if (tid < NC) ctrA[b * NC + tid] = 0u;
}

// ---- fallback fine hist (early-exits when boundary bin == TOPBIN) ----
__global__ __launch_bounds__(256)
void k_fine_fb(const unsigned* __restrict__ bits_lin,
               const unsigned* __restrict__ meta,
               unsigned short* __restrict__ p2) {
    const int b = blockIdx.y, blk = blockIdx.x, tid = threadIdx.x;
    const unsigned cbb = meta[b * 4 + 0];
    if (cbb == TOPBIN) return;                    // speculative hist already valid
    __shared__ unsigned h2[NF];
    for (int k = tid; k < NF; k += 256) h2[k] = 0u;
    __syncthreads();
    const int base = b * NITEMS;
    for (int i = blk * 256 + tid; i < NITEMS; i += NBLKA * 256) {
        unsigned bits = bits_lin[base + i];
        if (!bits) continue;
        float s = __uint_as_float(bits);
        if ((unsigned)cbin(s) == cbb) atomicAdd(&h2[fbin(s, (int)cbb)], 1u);
    }
    __syncthreads();
    const size_t row = (size_t)(b * NBLKA + blk) * NF;
    for (int k = tid; k < NF; k += 256) p2[row + k] = (unsigned short)h2[k];
}

// ---- coalesced reduce of 256 fine partial rows ----
__global__ __launch_bounds__(256)
void k_reduce_fine(const unsigned short* __restrict__ p2,
                   unsigned* __restrict__ red2) {
    const int b = blockIdx.y;
    const int g = blockIdx.x * 256 + threadIdx.x;     // grid.x = NF/256 = 16
    const unsigned short* p = p2 + (size_t)b * NBLKA * NF + g;
    unsigned s = 0;
    for (int k = 0; k < NBLKA; ++k) s += p[(size_t)k * NF];
    red2[b * NF + g] = s;
}

// ---- scan2: parallel suffix scan over 4096 reduced fine bins ----
__global__ __launch_bounds__(1024)
void k_scan2(const unsigned* __restrict__ red2,
             unsigned* __restrict__ fhist,
             unsigned* __restrict__ fsuf,
             unsigned* __restrict__ ctrB,
             unsigned* __restrict__ meta,
             int K) {
    const int b = blockIdx.x, tid = threadIdx.x;
    __shared__ unsigned sc[1024];
    const int binbase = 4 * (1023 - tid);
    const uint4 v = *(const uint4*)(red2 + b * NF + binbase);
    unsigned cw[4] = {v.w, v.z, v.y, v.x};            // descending bin order
    unsigned pin[4];
    unsigned run = 0;
    #pragma unroll
    for (int k = 0; k < 4; k++) { run += cw[k]; pin[k] = run; }
    sc[tid] = run;
    __syncthreads();
    unsigned x = run;
    for (int off = 1; off < 1024; off <<= 1) {
        unsigned t = (tid >= off) ? sc[tid - off] : 0u;
        __syncthreads();
        x += t;
        sc[tid] = x;
        __syncthreads();
    }
    const unsigned exclBase = x - run;
    const unsigned nAb = meta[b * 4 + 1];
    #pragma unroll
    for (int k = 0; k < 4; k++) {
        int g = binbase + (3 - k);
        unsigned excl = exclBase + pin[k] - cw[k];
        fsuf[b * NF + g] = excl;
        fhist[b * NF + g] = cw[k];
        unsigned t0 = nAb + excl;
        if (t0 < (unsigned)K && t0 + cw[k] >= (unsigned)K) {
            meta[b * 4 + 2] = (unsigned)g;
            meta[b * 4 + 3] = t0 + cw[k];
        }
    }
    if (tid == 0 && nAb + sc[1023] < (unsigned)K) {
        meta[b * 4 + 2] = 0u;
        meta[b * 4 + 3] = nAb + sc[1023];
    }
    ctrB[b * NF + tid * 4 + 0] = 0u;
    ctrB[b * NF + tid * 4 + 1] = 0u;
    ctrB[b * NF + tid * 4 + 2] = 0u;
    ctrB[b * NF + tid * 4 + 3] = 0u;
}

// ---- compact candidates into (tiny) segmented slots ----
__global__ __launch_bounds__(512)
void k_compact(const uint4* __restrict__ bits_arr,
               const unsigned* __restrict__ meta,
               const unsigned* __restrict__ csuf64,
               const unsigned* __restrict__ fsuf,
               unsigned* __restrict__ ctrA,
               unsigned* __restrict__ ctrB,
               ull* __restrict__ cand) {
    const int b = blockIdx.y;
    const unsigned cbb = meta[b * 4 + 0];
    const unsigned nAb = meta[b * 4 + 1];
    const unsigned fb  = meta[b * 4 + 2];
    const int base = b * NITEMS;
    for (int i0 = (blockIdx.x * 512 + threadIdx.x) * 4; i0 < NITEMS;
         i0 += NBLKF * 512 * 4) {
        uint4 v = bits_arr[(base + i0) >> 2];
        unsigned arr[4] = {v.x, v.y, v.z, v.w};
        #pragma unroll
        for (int j = 0; j < 4; j++) {
            unsigned bits = arr[j];
            if (!bits) continue;
            float s = __uint_as_float(bits);
            int g = cbin(s);
            if ((unsigned)g < cbb) continue;
            unsigned slot;
            if ((unsigned)g > cbb) {
                slot = csuf64[b * NC + g] + atomicAdd(&ctrA[b * NC + g], 1u);
            } else {
                int f = fbin(s, g);
                if ((unsigned)f < fb) continue;
                slot = nAb + fsuf[b * NF + f] + atomicAdd(&ctrB[b * NF + f], 1u);
            }
            if (slot < CAP)
                cand[(size_t)b * CAP + slot] =
                    ((ull)bits << 32) | (unsigned)(~(unsigned)(i0 + j));
        }
    }
}

// ---- rank within tiny segment, gather, write outputs ----
__global__ __launch_bounds__(256)
void k_rank_out(const ull* __restrict__ cand,
                const unsigned* __restrict__ meta,
                const unsigned* __restrict__ csuf64,
                const unsigned* __restrict__ chist64,
                const unsigned* __restrict__ fsuf,
                const unsigned* __restrict__ fhist,
                const float4* __restrict__ rps,
                float* __restrict__ out,
                int K) {
    const int b = blockIdx.y;
    unsigned total = meta[b * 4 + 3];
    if (total > CAP) total = CAP;
    const unsigned p = blockIdx.x * 256 + threadIdx.x;
    if (p >= total) return;
    const ull key = cand[(size_t)b * CAP + p];
    const unsigned bits = (unsigned)(key >> 32);
    const float s = __uint_as_float(bits);
    const unsigned cbb = meta[b * 4 + 0];
    const unsigned nAb = meta[b * 4 + 1];
    int g = cbin(s);
    unsigned sbase, scnt;
    if ((unsigned)g > cbb) {
        sbase = csuf64[b * NC + g];
        scnt  = chist64[b * NC + g];
    } else {
        int f = fbin(s, g);
        sbase = nAb + fsuf[b * NF + f];
        scnt  = fhist[b * NF + f];
    }
    unsigned send = sbase + scnt;
    if (send > total) send = total;
    unsigned rank = sbase;
    for (unsigned j = sbase; j < send; j++)
        rank += (cand[(size_t)b * CAP + j] > key) ? 1u : 0u;
    if (rank < (unsigned)K) {
        unsigned idx = ~((unsigned)key);
        float4 box = rps[(size_t)b * NITEMS + idx];
        float x1 = clip0(box.x - box.z * 0.5f, IMG_W);
        float x2 = clip0(box.x + box.z * 0.5f, IMG_W);
        float y1 = clip0(box.y - box.w * 0.5f, IMG_H);
        float y2 = clip0(box.y + box.w * 0.5f, IMG_H);
        float nw = x2 - x1, nh = y2 - y1;
        float nx = x1 + nw * 0.5f, ny = y1 + nh * 0.5f;
        ((float4*)out)[(size_t)b * K + rank] = make_float4(nx, ny, nw, nh);
        out[(size_t)BATCH * K * 4 + (size_t)b * K + rank] = s;
    }
}

extern "C" void kernel_launch(void* const* d_in, const int* in_sizes, int n_in,
                              void* d_out, int out_size, void* d_ws, size_t ws_size,
                              hipStream_t stream) {
    const float*  scores = (const float*)d_in[0];
    const float4* rps    = (const float4*)d_in[1];
    const int K = out_size / (BATCH * 5);               // 12000

    uint8_t* w = (uint8_t*)d_ws;
    uint4* bits_arr     = (uint4*)(w);                          // 32,000,000 B
    unsigned short* p1  = (unsigned short*)(w + 32000000);      // 262,144 B
    unsigned short* p2  = (unsigned short*)(w + 32300000);      // 16,777,216 B
    unsigned* red2      = (unsigned*)(w + 49100000);            // 131,072 B
    unsigned* chist64   = (unsigned*)(w + 49240000);            // 2 KiB
    unsigned* csuf64    = (unsigned*)(w + 49250000);            // 2 KiB
    unsigned* fhist     = (unsigned*)(w + 49260000);            // 128 KiB
    unsigned* fsuf      = (unsigned*)(w + 49400000);            // 128 KiB
    unsigned* ctrA      = (unsigned*)(w + 49540000);            // 2 KiB
    unsigned* ctrB      = (unsigned*)(w + 49550000);            // 128 KiB
    unsigned* meta      = (unsigned*)(w + 49690000);            // 128 B
    ull* cand           = (ull*)(w + 49700000);                 // 2 MiB

    k_bits<<<dim3(NBLKA, BATCH), dim3(256), 0, stream>>>(scores, rps, bits_arr, p1, p2);
    k_scan1<<<dim3(BATCH), dim3(256), 0, stream>>>(p1, chist64, csuf64, ctrA, meta, K);
    k_fine_fb<<<dim3(NBLKA, BATCH), dim3(256), 0, stream>>>((const unsigned*)bits_arr,
                                                            meta, p2);
    k_reduce_fine<<<dim3(NF / 256, BATCH), dim3(256), 0, stream>>>(p2, red2);
    k_scan2<<<dim3(BATCH), dim3(1024), 0, stream>>>(red2, fhist, fsuf, ctrB, meta, K);
    k_compact<<<dim3(NBLKF, BATCH), dim3(512), 0, stream>>>(bits_arr, meta, csuf64, fsuf,
                                                            ctrA, ctrB, cand);
    k_rank_out<<<dim3(CAP / 256, BATCH), dim3(256), 0, stream>>>(cand, meta, csuf64,
                                                                 chist64, fsuf, fhist,
                                                                 rps, (float*)d_out, K);
}